// Round 6
// baseline (38.373 us; speedup 1.0000x reference)
//
#include <hip/hip_runtime.h>
#include <cstddef>

namespace {

constexpr int B     = 512;
constexpr int C     = 2047;   // 2^(DEPTH+1) - 1
constexpr int L     = 4;
constexpr int DEPTH = 10;
constexpr int BLOCK = 512;
constexpr int NINT  = 1023;   // internal nodes (leaves' alphas are identically 0)

constexpr int EDGES   = 2046;  // parent->child edges
constexpr int ESTRIDE = 2048;  // padded edge stride per label-row stripe
// ws layout, in float4 units:
//   UpT[r][e] at  r*ESTRIDE + e      e = 2*p + ci  (child c = 2p+1+ci), rows of pairs[p][c]
//   DnT[r][e] at (4+r)*ESTRIDE + e   e = c - 1,    rows of pairs[c][parent(c)]
constexpr size_t WS_F4   = 8 * (size_t)ESTRIDE;
constexpr size_t WS_NEED = WS_F4 * 16;  // 262144 bytes

__device__ __forceinline__ float4 ld4(const float* p) {
    return *reinterpret_cast<const float4*>(p);
}
__device__ __forceinline__ void st4(float* p, float x, float y, float z, float w) {
    float4 v; v.x = x; v.y = y; v.z = z; v.w = w;
    *reinterpret_cast<float4*>(p) = v;
}

__device__ __forceinline__ float lse4(float v0, float v1, float v2, float v3) {
    const float m = fmaxf(fmaxf(v0, v1), fmaxf(v2, v3));
    const float s = __expf(v0 - m) + __expf(v1 - m) + __expf(v2 - m) + __expf(v3 - m);
    return m + __logf(s);
}

__device__ __forceinline__ void write_lsm(float* __restrict__ o,
                                          float g0, float g1, float g2, float g3) {
    const float z = lse4(g0, g1, g2, g3);
    st4(o, g0 - z, g1 - z, g2 - z, g3 - z);
}

// ---- one-shot compaction of the pairs hot set (2*2046 64B blocks) into SoA
// tables so the main kernel's pairs loads are wave-coalesced.
__global__ __launch_bounds__(256) void gather_pairs(
    const float4* __restrict__ pairs4,   // pairs viewed as float4[(C*C)*4]
    float4* __restrict__ ws)
{
    const int id  = blockIdx.x * 256 + threadIdx.x;   // [0, 16384)
    const int dir = id >> 13;
    const int r   = (id >> 11) & 3;
    const int e   = id & (ESTRIDE - 1);
    if (e >= EDGES) return;
    size_t src;
    if (dir == 0) {
        const int p = e >> 1;
        const int c = 2 * p + 1 + (e & 1);
        src = ((size_t)p * C + c) * 4 + r;            // pairs[p][c], row r
    } else {
        const int c = e + 1;
        const int p = (c - 1) >> 1;
        src = ((size_t)c * C + p) * 4 + r;            // pairs[c][p], row r
    }
    ws[(size_t)dir * (4 * ESTRIDE) + (size_t)r * ESTRIDE + e] = pairs4[src];
}

// One block per batch element. alphas for internal nodes in LDS; betas as a
// double-buffered per-level frontier; log_softmax fused into the downward
// sweep. COMPACT=true reads pairs rows from the coalesced SoA tables.
template <bool COMPACT>
__global__ __launch_bounds__(BLOCK, 4) void treecrf_kernel(
    const float* __restrict__ X,        // (B, C, L)
    const float* __restrict__ pairs,    // (C, C, L, L)
    const float4* __restrict__ cp,      // compacted tables (ws), or nullptr
    float* __restrict__ out)            // (B, C, L)
{
    __shared__ float alphas[NINT * L];
    __shared__ float fbo[512 * L];
    __shared__ float fbe[256 * L];

    const int b   = blockIdx.x;
    const int tid = threadIdx.x;
    const float* __restrict__ Xb = X + (size_t)b * (C * L);
    float* __restrict__ Ob       = out + (size_t)b * (C * L);

    // ---- upward levels 10..1: one thread per parent; fold both children.
    #pragma unroll 1
    for (int d = DEPTH; d >= 1; --d) {
        const int pn    = 1 << (d - 1);
        const int pbase = pn - 1;
        if (tid < pn) {
            const int p  = pbase + tid;
            const int c0 = 2 * p + 1;
            const float4 x0 = ld4(Xb + c0 * L);
            const float4 x1 = ld4(Xb + (c0 + 1) * L);
            float l00 = x0.x, l01 = x0.y, l02 = x0.z, l03 = x0.w;
            float l10 = x1.x, l11 = x1.y, l12 = x1.z, l13 = x1.w;
            if (d < DEPTH) {  // internal children carry alphas; leaves are 0
                const float4 a0 = ld4(&alphas[c0 * L]);
                const float4 a1 = ld4(&alphas[(c0 + 1) * L]);
                l00 += a0.x; l01 += a0.y; l02 += a0.z; l03 += a0.w;
                l10 += a1.x; l11 += a1.y; l12 += a1.z; l13 += a1.w;
            }
            float acc[4];
            #pragma unroll
            for (int r = 0; r < 4; ++r) {
                float4 t0, t1;
                if (COMPACT) {
                    // adjacent float4s: lane's 32B pair, consecutive lanes contiguous
                    t0 = cp[(size_t)r * ESTRIDE + 2 * p];
                    t1 = cp[(size_t)r * ESTRIDE + 2 * p + 1];
                } else {
                    t0 = ld4(pairs + ((size_t)p * C + c0) * 16 + r * 4);
                    t1 = ld4(pairs + ((size_t)p * C + c0 + 1) * 16 + r * 4);
                }
                acc[r] = lse4(t0.x + l00, t0.y + l01, t0.z + l02, t0.w + l03)
                       + lse4(t1.x + l10, t1.y + l11, t1.z + l12, t1.w + l13);
            }
            st4(&alphas[p * L], acc[0], acc[1], acc[2], acc[3]);
        }
        __syncthreads();
    }

    // ---- downward level 1 (+ root output). beta(root) = 0.
    if (tid < 2) {
        const int c = 1 + tid;
        const float4 x0 = ld4(Xb);  // X[root]
        float m[4];
        #pragma unroll
        for (int r = 0; r < 4; ++r) {
            const float4 t = COMPACT
                ? cp[(size_t)(4 + r) * ESTRIDE + (c - 1)]
                : ld4(pairs + (size_t)c * C * 16 + r * 4);
            m[r] = lse4(t.x + x0.x, t.y + x0.y, t.z + x0.z, t.w + x0.w);
        }
        st4(&fbo[(c - 1) * L], m[0], m[1], m[2], m[3]);
        const float4 xc = ld4(Xb + c * L);
        const float4 ac = ld4(&alphas[c * L]);
        write_lsm(Ob + c * L, xc.x + ac.x + m[0], xc.y + ac.y + m[1],
                              xc.z + ac.z + m[2], xc.w + ac.w + m[3]);
    } else if (tid == 2) {
        const float4 x0 = ld4(Xb);
        const float4 a0 = ld4(&alphas[0]);
        write_lsm(Ob, x0.x + a0.x, x0.y + a0.y, x0.z + a0.z, x0.w + a0.w);
    }
    __syncthreads();

    // ---- downward levels 2..10, output fused.
    #pragma unroll 1
    for (int d = 2; d <= DEPTH; ++d) {
        const int n     = 1 << d;
        const int base  = n - 1;
        const int pbase = (1 << (d - 1)) - 1;
        float* __restrict__ pbuf = ((d - 1) & 1) ? fbo : fbe;
        float* __restrict__ cbuf = (d & 1) ? fbo : fbe;
        for (int idx = tid; idx < n; idx += BLOCK) {
            const int c = base + idx;
            const int p = (c - 1) >> 1;
            const float4 xp = ld4(Xb + p * L);
            const float4 bp = ld4(&pbuf[(p - pbase) * L]);
            const float lp0 = xp.x + bp.x, lp1 = xp.y + bp.y;
            const float lp2 = xp.z + bp.z, lp3 = xp.w + bp.w;
            float m[4];
            #pragma unroll
            for (int r = 0; r < 4; ++r) {
                const float4 t = COMPACT
                    ? cp[(size_t)(4 + r) * ESTRIDE + (c - 1)]   // lane-consecutive
                    : ld4(pairs + ((size_t)c * C + p) * 16 + r * 4);
                m[r] = lse4(t.x + lp0, t.y + lp1, t.z + lp2, t.w + lp3);
            }
            if (d < DEPTH) st4(&cbuf[idx * L], m[0], m[1], m[2], m[3]);
            const float4 xc = ld4(Xb + c * L);
            float a0 = 0.f, a1 = 0.f, a2 = 0.f, a3 = 0.f;
            if (d <= 9) {
                const float4 ac = ld4(&alphas[c * L]);
                a0 = ac.x; a1 = ac.y; a2 = ac.z; a3 = ac.w;
            }
            write_lsm(Ob + c * L, xc.x + a0 + m[0], xc.y + a1 + m[1],
                                  xc.z + a2 + m[2], xc.w + a3 + m[3]);
        }
        if (d < DEPTH) __syncthreads();
    }
}

}  // namespace

extern "C" void kernel_launch(void* const* d_in, const int* in_sizes, int n_in,
                              void* d_out, int out_size, void* d_ws, size_t ws_size,
                              hipStream_t stream) {
    (void)in_sizes; (void)n_in; (void)out_size;
    const float* X     = (const float*)d_in[0];
    const float* pairs = (const float*)d_in[1];
    float* out         = (float*)d_out;

    if (ws_size >= WS_NEED) {
        float4* ws = (float4*)d_ws;
        gather_pairs<<<64, 256, 0, stream>>>((const float4*)pairs, ws);
        treecrf_kernel<true><<<B, BLOCK, 0, stream>>>(X, pairs, ws, out);
    } else {
        treecrf_kernel<false><<<B, BLOCK, 0, stream>>>(X, pairs, nullptr, out);
    }
}

// Round 7
// 34.593 us; speedup vs baseline: 1.1093x; 1.1093x over previous
//
#include <hip/hip_runtime.h>
#include <cstddef>

namespace {

constexpr int B     = 512;
constexpr int C     = 2047;   // 2^(DEPTH+1) - 1
constexpr int L     = 4;
constexpr int BLOCK = 256;
constexpr int NINT  = 1023;   // internal nodes (leaf alphas are identically 0)

__device__ __forceinline__ float4 ld4(const float* p) {
    return *reinterpret_cast<const float4*>(p);
}
__device__ __forceinline__ void st4f(float* p, const float4 v) {
    *reinterpret_cast<float4*>(p) = v;
}
__device__ __forceinline__ float4 add4(const float4 a, const float4 b) {
    float4 r; r.x = a.x + b.x; r.y = a.y + b.y; r.z = a.z + b.z; r.w = a.w + b.w;
    return r;
}

__device__ __forceinline__ float lse4(float v0, float v1, float v2, float v3) {
    const float m = fmaxf(fmaxf(v0, v1), fmaxf(v2, v3));
    const float s = __expf(v0 - m) + __expf(v1 - m) + __expf(v2 - m) + __expf(v3 - m);
    return m + __logf(s);
}

__device__ __forceinline__ void write_lsm(float* __restrict__ o, const float4 g) {
    const float z = lse4(g.x, g.y, g.z, g.w);
    float4 r; r.x = g.x - z; r.y = g.y - z; r.z = g.z - z; r.w = g.w - z;
    st4f(o, r);
}

// Upward message into parent p from BOTH children; lc0/lc1 = X+alpha of the
// two children. pairs[p][2p+1] and pairs[p][2p+2] are adjacent 64B blocks.
__device__ __forceinline__ float4 up2(const float* __restrict__ pairs, int p,
                                      const float4 lc0, const float4 lc1) {
    const int c0 = 2 * p + 1;
    const float* __restrict__ t = pairs + ((size_t)p * C + c0) * 16;
    float4 acc;
    {
        const float4 a = ld4(t + 0), bq = ld4(t + 16);
        acc.x = lse4(a.x + lc0.x, a.y + lc0.y, a.z + lc0.z, a.w + lc0.w)
              + lse4(bq.x + lc1.x, bq.y + lc1.y, bq.z + lc1.z, bq.w + lc1.w);
    }
    {
        const float4 a = ld4(t + 4), bq = ld4(t + 20);
        acc.y = lse4(a.x + lc0.x, a.y + lc0.y, a.z + lc0.z, a.w + lc0.w)
              + lse4(bq.x + lc1.x, bq.y + lc1.y, bq.z + lc1.z, bq.w + lc1.w);
    }
    {
        const float4 a = ld4(t + 8), bq = ld4(t + 24);
        acc.z = lse4(a.x + lc0.x, a.y + lc0.y, a.z + lc0.z, a.w + lc0.w)
              + lse4(bq.x + lc1.x, bq.y + lc1.y, bq.z + lc1.z, bq.w + lc1.w);
    }
    {
        const float4 a = ld4(t + 12), bq = ld4(t + 28);
        acc.w = lse4(a.x + lc0.x, a.y + lc0.y, a.z + lc0.z, a.w + lc0.w)
              + lse4(bq.x + lc1.x, bq.y + lc1.y, bq.z + lc1.z, bq.w + lc1.w);
    }
    return acc;
}

// Downward message into child c from parent p; lp = X[p] + beta[p].
__device__ __forceinline__ float4 dn_msg(const float* __restrict__ pairs,
                                         int c, int p, const float4 lp) {
    const float* __restrict__ t = pairs + ((size_t)c * C + p) * 16;
    const float4 t0 = ld4(t + 0), t1 = ld4(t + 4), t2 = ld4(t + 8), t3 = ld4(t + 12);
    float4 m;
    m.x = lse4(t0.x + lp.x, t0.y + lp.y, t0.z + lp.z, t0.w + lp.w);
    m.y = lse4(t1.x + lp.x, t1.y + lp.y, t1.z + lp.z, t1.w + lp.w);
    m.z = lse4(t2.x + lp.x, t2.y + lp.y, t2.z + lp.z, t2.w + lp.w);
    m.w = lse4(t3.x + lp.x, t3.y + lp.y, t3.z + lp.z, t3.w + lp.w);
    return m;
}

// One block (256 threads) per batch element. Wide levels (>=128 items) use
// block barriers; everything with <=64 items (up d=7..1, root, down d=1..6)
// runs wave-synchronously inside wave 0 with NO s_barrier. 7 barriers total
// vs 20 previously.
__global__ __launch_bounds__(BLOCK, 2) void treecrf_kernel(
    const float* __restrict__ X,      // (B, C, L)
    const float* __restrict__ pairs,  // (C, C, L, L)
    float* __restrict__ out)          // (B, C, L)
{
    __shared__ float alphas[NINT * L];  // 16368 B
    __shared__ float fbo[512 * L];      // beta frontier, down d=7/9 writes
    __shared__ float fbe[256 * L];      // beta frontier, down d=8 writes
    __shared__ float fbA[32 * L];       // wave-section frontier (odd d writes)
    __shared__ float fbB[64 * L];       // wave-section frontier (even d writes)

    const int b   = blockIdx.x;
    const int tid = threadIdx.x;
    const float* __restrict__ Xb = X + (size_t)b * (C * L);
    float* __restrict__ Ob       = out + (size_t)b * (C * L);

    // ---- up d=10: 512 leaf parents, 2 per thread (independent -> ILP).
    {
        int p = 511 + tid;
        const float4 l0 = ld4(Xb + (2 * p + 1) * L);
        const float4 l1 = ld4(Xb + (2 * p + 2) * L);
        int q = p + 256;
        const float4 m0 = ld4(Xb + (2 * q + 1) * L);
        const float4 m1 = ld4(Xb + (2 * q + 2) * L);
        st4f(&alphas[p * L], up2(pairs, p, l0, l1));
        st4f(&alphas[q * L], up2(pairs, q, m0, m1));
    }
    __syncthreads();

    // ---- up d=9: 256 parents.
    {
        const int p  = 255 + tid;
        const int c0 = 2 * p + 1;
        const float4 l0 = add4(ld4(Xb + c0 * L), ld4(&alphas[c0 * L]));
        const float4 l1 = add4(ld4(Xb + (c0 + 1) * L), ld4(&alphas[(c0 + 1) * L]));
        st4f(&alphas[p * L], up2(pairs, p, l0, l1));
    }
    __syncthreads();

    // ---- up d=8: 128 parents.
    if (tid < 128) {
        const int p  = 127 + tid;
        const int c0 = 2 * p + 1;
        const float4 l0 = add4(ld4(Xb + c0 * L), ld4(&alphas[c0 * L]));
        const float4 l1 = add4(ld4(Xb + (c0 + 1) * L), ld4(&alphas[(c0 + 1) * L]));
        st4f(&alphas[p * L], up2(pairs, p, l0, l1));
    }
    __syncthreads();

    // ================= wave-0 section: no block barriers =================
    if (tid < 64) {
        // up d=7..1 (pn = 64,32,16,8,4,2,1)
        #pragma unroll 1
        for (int pn = 64; pn >= 1; pn >>= 1) {
            if (tid < pn) {
                const int p  = pn - 1 + tid;
                const int c0 = 2 * p + 1;
                const float4 l0 = add4(ld4(Xb + c0 * L), ld4(&alphas[c0 * L]));
                const float4 l1 = add4(ld4(Xb + (c0 + 1) * L), ld4(&alphas[(c0 + 1) * L]));
                st4f(&alphas[p * L], up2(pairs, p, l0, l1));
            }
            __builtin_amdgcn_wave_barrier();
        }

        const float4 x0 = ld4(Xb);  // X[root]
        if (tid == 0) {
            write_lsm(Ob, add4(x0, ld4(&alphas[0])));  // root: beta = 0
        }
        // down d=1 (n=2): beta(root)=0 -> lp = X[root]
        if (tid < 2) {
            const int c = 1 + tid;
            const float4 m = dn_msg(pairs, c, 0, x0);
            st4f(&fbA[tid * L], m);
            write_lsm(Ob + c * L,
                      add4(add4(ld4(Xb + c * L), ld4(&alphas[c * L])), m));
        }
        __builtin_amdgcn_wave_barrier();

        // down d=2..6 (n = 4..64), frontier ping-pongs fbA <-> fbB.
        #pragma unroll 1
        for (int d = 2; d <= 6; ++d) {
            const int n     = 1 << d;
            const int base  = n - 1;
            const int pbase = (1 << (d - 1)) - 1;
            const float* __restrict__ pb = (d & 1) ? fbB : fbA;
            float* __restrict__       cb = (d & 1) ? fbA : fbB;
            if (tid < n) {
                const int c = base + tid;
                const int p = (c - 1) >> 1;
                const float4 lp = add4(ld4(Xb + p * L), ld4(&pb[(p - pbase) * L]));
                const float4 m  = dn_msg(pairs, c, p, lp);
                st4f(&cb[tid * L], m);
                write_lsm(Ob + c * L,
                          add4(add4(ld4(Xb + c * L), ld4(&alphas[c * L])), m));
            }
            __builtin_amdgcn_wave_barrier();
        }
    }
    __syncthreads();
    // =====================================================================

    // ---- down d=7: n=128, parents (depth 6) in fbB.
    if (tid < 128) {
        const int c = 127 + tid;
        const int p = (c - 1) >> 1;           // pbase = 63
        const float4 lp = add4(ld4(Xb + p * L), ld4(&fbB[(p - 63) * L]));
        const float4 m  = dn_msg(pairs, c, p, lp);
        st4f(&fbo[tid * L], m);
        write_lsm(Ob + c * L, add4(add4(ld4(Xb + c * L), ld4(&alphas[c * L])), m));
    }
    __syncthreads();

    // ---- down d=8: n=256.
    {
        const int c = 255 + tid;
        const int p = (c - 1) >> 1;           // pbase = 127
        const float4 lp = add4(ld4(Xb + p * L), ld4(&fbo[(p - 127) * L]));
        const float4 m  = dn_msg(pairs, c, p, lp);
        st4f(&fbe[tid * L], m);
        write_lsm(Ob + c * L, add4(add4(ld4(Xb + c * L), ld4(&alphas[c * L])), m));
    }
    __syncthreads();

    // ---- down d=9: n=512, 2 per thread.
    #pragma unroll
    for (int k = 0; k < 2; ++k) {
        const int idx = tid + k * 256;
        const int c   = 511 + idx;
        const int p   = (c - 1) >> 1;         // pbase = 255
        const float4 lp = add4(ld4(Xb + p * L), ld4(&fbe[(p - 255) * L]));
        const float4 m  = dn_msg(pairs, c, p, lp);
        st4f(&fbo[idx * L], m);
        write_lsm(Ob + c * L, add4(add4(ld4(Xb + c * L), ld4(&alphas[c * L])), m));
    }
    __syncthreads();

    // ---- down d=10: n=1024 leaves (alpha = 0), 4 per thread.
    #pragma unroll
    for (int k = 0; k < 4; ++k) {
        const int idx = tid + k * 256;
        const int c   = 1023 + idx;
        const int p   = (c - 1) >> 1;         // pbase = 511
        const float4 lp = add4(ld4(Xb + p * L), ld4(&fbo[(p - 511) * L]));
        const float4 m  = dn_msg(pairs, c, p, lp);
        write_lsm(Ob + c * L, add4(ld4(Xb + c * L), m));
    }
}

}  // namespace

extern "C" void kernel_launch(void* const* d_in, const int* in_sizes, int n_in,
                              void* d_out, int out_size, void* d_ws, size_t ws_size,
                              hipStream_t stream) {
    (void)in_sizes; (void)n_in; (void)out_size; (void)d_ws; (void)ws_size;
    const float* X     = (const float*)d_in[0];
    const float* pairs = (const float*)d_in[1];
    float* out         = (float*)d_out;
    treecrf_kernel<<<B, BLOCK, 0, stream>>>(X, pairs, out);
}